// Round 3
// baseline (94.609 us; speedup 1.0000x reference)
//
#include <hip/hip_runtime.h>
#include <hip/hip_bf16.h>

#define NCLS 200
#define NPAD 208
#define NT 13          // 208 / 16 class tiles
#define DIM 512
#define NSAMP 32768
#define CAP 64         // per-wave list capacity (2048-sample segment, expect ~10)

typedef __attribute__((ext_vector_type(4))) float f32x4;
typedef __attribute__((ext_vector_type(4))) int   i32x4;
typedef __attribute__((ext_vector_type(8))) short bf16x8;

__device__ inline short bf16s(float x) {
  __hip_bfloat16 h = __float2bfloat16(x);
  return *reinterpret_cast<short*>(&h);
}

// ---------------- Kernel 1a: per-(class, sample-half) partial sums -------------
// 400 blocks = 200 classes x 2 halves, 512 threads = 8 waves.
// Wave w scans its 2048-sample segment barrier-free (intra-wave ballot rank),
// gathers+sums matching rows, one barrier to combine 8 wave partials.
__global__ __launch_bounds__(512) void k_psum(
    const float* __restrict__ feat, const int* __restrict__ labels,
    float* __restrict__ psum, int* __restrict__ pcnt)
{
  const int bx = blockIdx.x;
  const int c = bx >> 1, h = bx & 1;
  const int tid = threadIdx.x;
  const int lane = tid & 63;
  const int w = tid >> 6;

  __shared__ int   lists[8][CAP];
  __shared__ int   cnts[8];
  __shared__ float partial[8][DIM];

  // phase 1: barrier-free per-wave match list (fixed order within wave)
  int cnt = 0;
  const int segbase = h * (NSAMP / 2) + w * (NSAMP / 16);
  for (int i = 0; i < (NSAMP / 16) / 256; ++i) {          // 8 iters
    const int base = segbase + i * 256 + lane * 4;
    const i32x4 lab4 = *(const i32x4*)(labels + base);
    #pragma unroll
    for (int u = 0; u < 4; ++u) {
      const bool m = (lab4[u] == c);
      const unsigned long long bal = __ballot(m);
      if (m) {
        const int pos = cnt + __popcll(bal & ((1ull << lane) - 1ull));
        if (pos < CAP) lists[w][pos] = base + u;
      }
      cnt += __popcll(bal);
    }
  }
  if (cnt > CAP) cnt = CAP;
  if (lane == 0) cnts[w] = cnt;

  // phase 2: gather-sum this wave's rows; lane owns dims [lane*8, lane*8+8)
  float acc[8];
  #pragma unroll
  for (int q = 0; q < 8; ++q) acc[q] = 0.f;
  for (int j = 0; j < cnt; ++j) {
    const int r = lists[w][j];
    const f32x4 a = *(const f32x4*)(feat + (size_t)r * DIM + lane * 8);
    const f32x4 b = *(const f32x4*)(feat + (size_t)r * DIM + lane * 8 + 4);
    acc[0] += a[0]; acc[1] += a[1]; acc[2] += a[2]; acc[3] += a[3];
    acc[4] += b[0]; acc[5] += b[1]; acc[6] += b[2]; acc[7] += b[3];
  }
  #pragma unroll
  for (int q = 0; q < 8; ++q) partial[w][lane * 8 + q] = acc[q];
  __syncthreads();

  // phase 3: combine 8 wave partials in fixed order; thread owns dim = tid
  int total = 0;
  #pragma unroll
  for (int u = 0; u < 8; ++u) total += cnts[u];
  float s = 0.f;
  #pragma unroll
  for (int u = 0; u < 8; ++u) s += partial[u][tid];
  psum[(size_t)(h * NCLS + c) * DIM + tid] = s;
  if (tid == 0) pcnt[h * NCLS + c] = total;
}

// ---------------- Kernel 1b: combine halves -> bf16 prototypes + p2 ------------
__global__ __launch_bounds__(256) void k_pcomb(
    const float* __restrict__ psum, const int* __restrict__ pcnt,
    unsigned short* __restrict__ protoB, float* __restrict__ p2out)
{
  const int c = blockIdx.x;
  const int tid = threadIdx.x;
  if (c >= NCLS) {
    protoB[c * DIM + tid] = 0;        // bf16 +0.0
    protoB[c * DIM + 256 + tid] = 0;
    if (tid == 0) p2out[c] = 1e30f;   // never wins argmin
    return;
  }
  __shared__ float red[256];
  const float a0 = psum[(size_t)c * DIM + tid] + psum[(size_t)(NCLS + c) * DIM + tid];
  const float a1 = psum[(size_t)c * DIM + 256 + tid] + psum[(size_t)(NCLS + c) * DIM + 256 + tid];
  const int total = pcnt[c] + pcnt[NCLS + c];
  const float inv = 1.0f / ((float)total + 1e-8f);   // counts + EPS
  const float p0 = a0 * inv, p1 = a1 * inv;
  protoB[c * DIM + tid] = (unsigned short)bf16s(p0);
  protoB[c * DIM + 256 + tid] = (unsigned short)bf16s(p1);

  red[tid] = p0 * p0 + p1 * p1;
  __syncthreads();
  for (int s = 128; s > 0; s >>= 1) {
    if (tid < s) red[tid] += red[tid + s];
    __syncthreads();
  }
  if (tid == 0) p2out[c] = red[0];
}

// ---------------- Kernel 2: scores (MFMA GEMM) + argmin + per-sample loss ------
// 2048 waves (512 blocks); each wave: 16 samples x 208 classes.
// A = features (fp32 loaded, bf16 in-register), B = bf16 prototypes, f2 on the fly.
__global__ __launch_bounds__(256) void k_score(
    const float* __restrict__ feat, const int* __restrict__ labels,
    const unsigned short* __restrict__ protoB, const float* __restrict__ p2,
    float* __restrict__ partials)
{
  const int tid = threadIdx.x;
  const int lane = tid & 63;
  const int wid = blockIdx.x * 4 + (tid >> 6);   // 0..2047
  const int base = wid * 16;
  const int lr = lane & 15;    // A row / B col (local)
  const int kg = lane >> 4;    // k-group

  f32x4 acc[NT];
  #pragma unroll
  for (int t = 0; t < NT; ++t) acc[t] = f32x4{0.f, 0.f, 0.f, 0.f};
  float f2a = 0.f;

  const float* arow = feat + (size_t)(base + lr) * DIM;

  for (int k = 0; k < 16; ++k) {
    const int koff = k * 32 + kg * 8;
    const f32x4 fa0 = *(const f32x4*)(arow + koff);
    const f32x4 fa1 = *(const f32x4*)(arow + koff + 4);

    f2a += fa0[0]*fa0[0] + fa0[1]*fa0[1] + fa0[2]*fa0[2] + fa0[3]*fa0[3]
         + fa1[0]*fa1[0] + fa1[1]*fa1[1] + fa1[2]*fa1[2] + fa1[3]*fa1[3];

    bf16x8 A0;
    A0[0] = bf16s(fa0[0]); A0[1] = bf16s(fa0[1]); A0[2] = bf16s(fa0[2]); A0[3] = bf16s(fa0[3]);
    A0[4] = bf16s(fa1[0]); A0[5] = bf16s(fa1[1]); A0[6] = bf16s(fa1[2]); A0[7] = bf16s(fa1[3]);

    #pragma unroll
    for (int t = 0; t < NT; ++t) {
      const bf16x8 Bf = *(const bf16x8*)(protoB + (size_t)(t * 16 + lr) * DIM + koff);
      acc[t] = __builtin_amdgcn_mfma_f32_16x16x32_bf16(A0, Bf, acc[t], 0, 0, 0);
    }
  }

  // f2 held per (lr = sample row); reduce across the 4 k-groups
  f2a += __shfl_xor(f2a, 16);
  f2a += __shfl_xor(f2a, 32);

  float p2v[NT];
  #pragma unroll
  for (int t = 0; t < NT; ++t) p2v[t] = p2[t * 16 + lr];

  float lsum = 0.f;
  #pragma unroll
  for (int r = 0; r < 4; ++r) {
    const int srow = kg * 4 + r;                  // C/D row = local sample
    const float f2s = __shfl(f2a, srow);
    const int samp = base + srow;
    const int lab = labels[samp];
    float bestd = 1e38f; int bestc = 1 << 30;
    float posd = -1.f;
    #pragma unroll
    for (int t = 0; t < NT; ++t) {
      const int cidx = t * 16 + lr;               // C/D col = class
      const float s = acc[t][r];
      const float d2 = fmaxf(f2s + p2v[t] - 2.0f * s, 0.0f);
      if (cidx == lab) posd = d2;
      else if (cidx < NCLS &&
               (d2 < bestd || (d2 == bestd && cidx < bestc))) { bestd = d2; bestc = cidx; }
    }
    // reduce across the 16 lanes of this row-group (xor stays within group)
    #pragma unroll
    for (int sft = 1; sft < 16; sft <<= 1) {
      const float od = __shfl_xor(bestd, sft);
      const int   oc = __shfl_xor(bestc, sft);
      const float op = __shfl_xor(posd, sft);
      if (od < bestd || (od == bestd && oc < bestc)) { bestd = od; bestc = oc; }
      posd = fmaxf(posd, op);
    }
    const float dap = posd, dan = bestd;
    const float dapn = dap / (dap + dan + 1e-8f);
    const float dann = dan / (dapn + dan + 1e-8f);   // sequential normalization
    const float ps = fmaxf(0.f, 1.5f * dapn - 0.8f * dann + 0.6f);
    if (lr == 0) lsum += ps;   // one lane per row-group accumulates
  }
  lsum += __shfl_xor(lsum, 16);
  lsum += __shfl_xor(lsum, 32);
  if (lane == 0) partials[wid] = lsum;
}

// ---------------- Kernel 3: deterministic final reduce -------------------------
__global__ __launch_bounds__(256) void k_finish(const float* __restrict__ partials,
                                                float* __restrict__ out)
{
  __shared__ float red[256];
  const int tid = threadIdx.x;
  float s = 0.f;
  #pragma unroll
  for (int j = 0; j < 8; ++j) s += partials[tid + j * 256];
  red[tid] = s;
  __syncthreads();
  for (int st = 128; st > 0; st >>= 1) {
    if (tid < st) red[tid] += red[tid + st];
    __syncthreads();
  }
  if (tid == 0) out[0] = fabsf(0.2f * (red[0] / (float)NSAMP));
}

extern "C" void kernel_launch(void* const* d_in, const int* in_sizes, int n_in,
                              void* d_out, int out_size, void* d_ws, size_t ws_size,
                              hipStream_t stream) {
  const float* feat = (const float*)d_in[0];
  const int* labels = (const int*)d_in[1];
  float* out = (float*)d_out;

  char* ws = (char*)d_ws;
  unsigned short* protoB = (unsigned short*)ws;                  // 208*512*2 = 212992 B
  float* p2 = (float*)(ws + 212992);                             // 832 B
  float* partials = (float*)(ws + 214016);                       // 2048 floats = 8192 B
  float* psum = (float*)(ws + 222464);                           // 2*200*512*4 = 819200 B
  int* pcnt = (int*)(ws + 222464 + 819200);                      // 400 ints

  k_psum<<<2 * NCLS, 512, 0, stream>>>(feat, labels, psum, pcnt);
  k_pcomb<<<NPAD, 256, 0, stream>>>(psum, pcnt, protoB, p2);
  k_score<<<512, 256, 0, stream>>>(feat, labels, protoB, p2, partials);
  k_finish<<<1, 256, 0, stream>>>(partials, out);
}

// Round 4
// 54.691 us; speedup vs baseline: 1.7299x; 1.7299x over previous
//
#include <hip/hip_runtime.h>
#include <hip/hip_bf16.h>

#define NCLS 200
#define NPAD 208
#define NT 13          // 208 / 16 class tiles
#define DIM 512
#define NSAMP 32768
#define CAP 64         // per-wave list capacity (2048-sample segment, expect ~10)
#define BM 128         // sample rows per block
#define BK 32          // k-chunk per iteration
#define KIT 16         // DIM / BK
#define BSTR 40        // B LDS row stride in ushorts (80 B, 16B-aligned, conflict-free)

typedef __attribute__((ext_vector_type(4))) float f32x4;
typedef __attribute__((ext_vector_type(4))) int   i32x4;
typedef __attribute__((ext_vector_type(8))) short bf16x8;

__device__ inline short bf16s(float x) {
  __hip_bfloat16 h = __float2bfloat16(x);
  return *reinterpret_cast<short*>(&h);
}

__device__ inline bf16x8 pack8(f32x4 a, f32x4 b) {
  bf16x8 r;
  r[0] = bf16s(a[0]); r[1] = bf16s(a[1]); r[2] = bf16s(a[2]); r[3] = bf16s(a[3]);
  r[4] = bf16s(b[0]); r[5] = bf16s(b[1]); r[6] = bf16s(b[2]); r[7] = bf16s(b[3]);
  return r;
}

__device__ inline float sumsq(f32x4 a) {
  return a[0]*a[0] + a[1]*a[1] + a[2]*a[2] + a[3]*a[3];
}

// ---------------- Kernel 1a: per-(class, sample-half) partial sums -------------
__global__ __launch_bounds__(512) void k_psum(
    const float* __restrict__ feat, const int* __restrict__ labels,
    float* __restrict__ psum, int* __restrict__ pcnt)
{
  const int bx = blockIdx.x;
  const int c = bx >> 1, h = bx & 1;
  const int tid = threadIdx.x;
  const int lane = tid & 63;
  const int w = tid >> 6;

  __shared__ int   lists[8][CAP];
  __shared__ int   cnts[8];
  __shared__ float partial[8][DIM];

  int cnt = 0;
  const int segbase = h * (NSAMP / 2) + w * (NSAMP / 16);
  for (int i = 0; i < (NSAMP / 16) / 256; ++i) {          // 8 iters
    const int base = segbase + i * 256 + lane * 4;
    const i32x4 lab4 = *(const i32x4*)(labels + base);
    #pragma unroll
    for (int u = 0; u < 4; ++u) {
      const bool m = (lab4[u] == c);
      const unsigned long long bal = __ballot(m);
      if (m) {
        const int pos = cnt + __popcll(bal & ((1ull << lane) - 1ull));
        if (pos < CAP) lists[w][pos] = base + u;
      }
      cnt += __popcll(bal);
    }
  }
  if (cnt > CAP) cnt = CAP;
  if (lane == 0) cnts[w] = cnt;

  float acc[8];
  #pragma unroll
  for (int q = 0; q < 8; ++q) acc[q] = 0.f;
  for (int j = 0; j < cnt; ++j) {
    const int r = lists[w][j];
    const f32x4 a = *(const f32x4*)(feat + (size_t)r * DIM + lane * 8);
    const f32x4 b = *(const f32x4*)(feat + (size_t)r * DIM + lane * 8 + 4);
    acc[0] += a[0]; acc[1] += a[1]; acc[2] += a[2]; acc[3] += a[3];
    acc[4] += b[0]; acc[5] += b[1]; acc[6] += b[2]; acc[7] += b[3];
  }
  #pragma unroll
  for (int q = 0; q < 8; ++q) partial[w][lane * 8 + q] = acc[q];
  __syncthreads();

  int total = 0;
  #pragma unroll
  for (int u = 0; u < 8; ++u) total += cnts[u];
  float s = 0.f;
  #pragma unroll
  for (int u = 0; u < 8; ++u) s += partial[u][tid];
  psum[(size_t)(h * NCLS + c) * DIM + tid] = s;
  if (tid == 0) pcnt[h * NCLS + c] = total;
}

// ---------------- Kernel 1b: combine halves -> bf16 prototypes + p2 ------------
__global__ __launch_bounds__(256) void k_pcomb(
    const float* __restrict__ psum, const int* __restrict__ pcnt,
    unsigned short* __restrict__ protoB, float* __restrict__ p2out)
{
  const int c = blockIdx.x;
  const int tid = threadIdx.x;
  if (c >= NCLS) {
    protoB[c * DIM + tid] = 0;        // bf16 +0.0
    protoB[c * DIM + 256 + tid] = 0;
    if (tid == 0) p2out[c] = 1e30f;   // never wins argmin
    return;
  }
  __shared__ float red[256];
  const float a0 = psum[(size_t)c * DIM + tid] + psum[(size_t)(NCLS + c) * DIM + tid];
  const float a1 = psum[(size_t)c * DIM + 256 + tid] + psum[(size_t)(NCLS + c) * DIM + 256 + tid];
  const int total = pcnt[c] + pcnt[NCLS + c];
  const float inv = 1.0f / ((float)total + 1e-8f);   // counts + EPS
  const float p0 = a0 * inv, p1 = a1 * inv;
  protoB[c * DIM + tid] = (unsigned short)bf16s(p0);
  protoB[c * DIM + 256 + tid] = (unsigned short)bf16s(p1);

  red[tid] = p0 * p0 + p1 * p1;
  __syncthreads();
  for (int s = 128; s > 0; s >>= 1) {
    if (tid < s) red[tid] += red[tid + s];
    __syncthreads();
  }
  if (tid == 0) p2out[c] = red[0];
}

// ---------------- Kernel 2: LDS double-buffered MFMA GEMM + argmin + loss ------
// 256 blocks x 256 thr (4 waves). Block: 128 samples x 208 classes, K=512.
// Per iter: stage next A (fp32->bf16, XOR-swizzled) + next B (padded rows) into
// LDS buf^1 while computing MFMAs from buf. One barrier/iter (2-phase template).
// f2 computed EXACTLY in fp32 by staging threads (fixed row-half ownership).
__global__ __launch_bounds__(256) void k_score(
    const float* __restrict__ feat, const int* __restrict__ labels,
    const unsigned short* __restrict__ protoB, const float* __restrict__ p2,
    float* __restrict__ partials)
{
  __shared__ __align__(16) unsigned short As[2][BM * BK];     // bf16, swizzled units
  __shared__ __align__(16) unsigned short Bs[2][NPAD * BSTR]; // bf16, 80B row stride
  __shared__ float f2s[BM][2];

  const int tid = threadIdx.x;
  const int lane = tid & 63;
  const int w = tid >> 6;           // wave 0..3; wave owns rows [w*32, w*32+32)
  const int lr = lane & 15;
  const int kg = lane >> 4;

  const int blockRow = blockIdx.x * BM;

  // staging roles: A = 2 threads/row (row = tid>>1, half = tid&1)
  const int arow = tid >> 1;
  const int ahalf = tid & 1;
  const float* agp = feat + (size_t)(blockRow + arow) * DIM + ahalf * 16;
  const int brow = tid;             // B: thread t stages proto row t (t < 208)
  const f32x4* bgp = (const f32x4*)(protoB + (size_t)brow * DIM);

  // A swizzle: logical 16B-unit u of row r stored at phys unit u ^ (r&3)
  const int aw0 = (( (ahalf*2    ) ^ (arow & 3)) * 8);
  const int aw1 = (( (ahalf*2 + 1) ^ (arow & 3)) * 8);

  float f2part = 0.f;

  // ---- prologue: stage k-chunk 0 into buf 0 ----
  {
    const f32x4 a0 = *(const f32x4*)(agp);
    const f32x4 a1 = *(const f32x4*)(agp + 4);
    const f32x4 a2 = *(const f32x4*)(agp + 8);
    const f32x4 a3 = *(const f32x4*)(agp + 12);
    f2part += sumsq(a0) + sumsq(a1) + sumsq(a2) + sumsq(a3);
    *(bf16x8*)&As[0][arow * BK + aw0] = pack8(a0, a1);
    *(bf16x8*)&As[0][arow * BK + aw1] = pack8(a2, a3);
    if (brow < NPAD) {
      const f32x4 b0 = bgp[0], b1 = bgp[1], b2 = bgp[2], b3 = bgp[3];
      *(f32x4*)&Bs[0][brow * BSTR + 0]  = b0;
      *(f32x4*)&Bs[0][brow * BSTR + 8]  = b1;
      *(f32x4*)&Bs[0][brow * BSTR + 16] = b2;
      *(f32x4*)&Bs[0][brow * BSTR + 24] = b3;
    }
  }
  __syncthreads();

  f32x4 acc0[NT], acc1[NT];
  #pragma unroll
  for (int n = 0; n < NT; ++n) {
    acc0[n] = f32x4{0.f, 0.f, 0.f, 0.f};
    acc1[n] = f32x4{0.f, 0.f, 0.f, 0.f};
  }

  const int r0 = w * 32 + lr;       // A-tile local rows for this lane's frags
  const int r1 = r0 + 16;
  const int ar0 = r0 * BK + ((kg ^ (r0 & 3)) * 8);
  const int ar1 = r1 * BK + ((kg ^ (r1 & 3)) * 8);

  #pragma unroll 2
  for (int t = 0; t < KIT; ++t) {
    const int cur = t & 1;
    f32x4 a0, a1, a2, a3, b0, b1, b2, b3;
    if (t < KIT - 1) {              // issue next-chunk global loads EARLY
      const float* ag = agp + (t + 1) * BK;
      a0 = *(const f32x4*)(ag);
      a1 = *(const f32x4*)(ag + 4);
      a2 = *(const f32x4*)(ag + 8);
      a3 = *(const f32x4*)(ag + 12);
      if (brow < NPAD) {
        const f32x4* bg = bgp + (t + 1) * 4;
        b0 = bg[0]; b1 = bg[1]; b2 = bg[2]; b3 = bg[3];
      }
    }
    // compute from buf[cur]
    const bf16x8 Af0 = *(const bf16x8*)&As[cur][ar0];
    const bf16x8 Af1 = *(const bf16x8*)&As[cur][ar1];
    #pragma unroll
    for (int n = 0; n < NT; ++n) {
      const bf16x8 Bf = *(const bf16x8*)&Bs[cur][(n * 16 + lr) * BSTR + kg * 8];
      acc0[n] = __builtin_amdgcn_mfma_f32_16x16x32_bf16(Af0, Bf, acc0[n], 0, 0, 0);
      acc1[n] = __builtin_amdgcn_mfma_f32_16x16x32_bf16(Af1, Bf, acc1[n], 0, 0, 0);
    }
    if (t < KIT - 1) {              // write next chunk LATE (loads have landed)
      const int nb = cur ^ 1;
      f2part += sumsq(a0) + sumsq(a1) + sumsq(a2) + sumsq(a3);
      *(bf16x8*)&As[nb][arow * BK + aw0] = pack8(a0, a1);
      *(bf16x8*)&As[nb][arow * BK + aw1] = pack8(a2, a3);
      if (brow < NPAD) {
        *(f32x4*)&Bs[nb][brow * BSTR + 0]  = b0;
        *(f32x4*)&Bs[nb][brow * BSTR + 8]  = b1;
        *(f32x4*)&Bs[nb][brow * BSTR + 16] = b2;
        *(f32x4*)&Bs[nb][brow * BSTR + 24] = b3;
      }
      __syncthreads();
    }
  }

  // publish exact per-row-half f2; combine deterministically (half0 + half1)
  f2s[arow][ahalf] = f2part;
  __syncthreads();

  float p2v[NT];
  #pragma unroll
  for (int n = 0; n < NT; ++n) p2v[n] = p2[n * 16 + lr];

  float lsum = 0.f;
  #pragma unroll
  for (int m = 0; m < 2; ++m) {
    #pragma unroll
    for (int r = 0; r < 4; ++r) {
      const int srow = kg * 4 + r;                    // C/D row within 16-tile
      const int lrow = w * 32 + m * 16 + srow;        // block-local sample row
      const float f2v = f2s[lrow][0] + f2s[lrow][1];
      const int samp = blockRow + lrow;
      const int lab = labels[samp];
      float bestd = 1e38f; int bestc = 1 << 30;
      float posd = -1.f;
      #pragma unroll
      for (int n = 0; n < NT; ++n) {
        const int cidx = n * 16 + lr;                 // C/D col = class
        const float sc = (m == 0) ? acc0[n][r] : acc1[n][r];
        const float d2 = fmaxf(f2v + p2v[n] - 2.0f * sc, 0.0f);
        if (cidx == lab) posd = d2;
        else if (cidx < NCLS &&
                 (d2 < bestd || (d2 == bestd && cidx < bestc))) { bestd = d2; bestc = cidx; }
      }
      #pragma unroll
      for (int sft = 1; sft < 16; sft <<= 1) {        // reduce within 16-lane group
        const float od = __shfl_xor(bestd, sft);
        const int   oc = __shfl_xor(bestc, sft);
        const float op = __shfl_xor(posd, sft);
        if (od < bestd || (od == bestd && oc < bestc)) { bestd = od; bestc = oc; }
        posd = fmaxf(posd, op);
      }
      const float dap = posd, dan = bestd;
      const float dapn = dap / (dap + dan + 1e-8f);
      const float dann = dan / (dapn + dan + 1e-8f);  // sequential normalization
      const float ps = fmaxf(0.f, 1.5f * dapn - 0.8f * dann + 0.6f);
      if (lr == 0) lsum += ps;
    }
  }
  lsum += __shfl_xor(lsum, 16);
  lsum += __shfl_xor(lsum, 32);
  if (lane == 0) partials[blockIdx.x * 4 + w] = lsum;
}

// ---------------- Kernel 3: deterministic final reduce (1024 partials) ---------
__global__ __launch_bounds__(256) void k_finish(const float* __restrict__ partials,
                                                float* __restrict__ out)
{
  __shared__ float red[256];
  const int tid = threadIdx.x;
  float s = 0.f;
  #pragma unroll
  for (int j = 0; j < 4; ++j) s += partials[tid + j * 256];
  red[tid] = s;
  __syncthreads();
  for (int st = 128; st > 0; st >>= 1) {
    if (tid < st) red[tid] += red[tid + st];
    __syncthreads();
  }
  if (tid == 0) out[0] = fabsf(0.2f * (red[0] / (float)NSAMP));
}

extern "C" void kernel_launch(void* const* d_in, const int* in_sizes, int n_in,
                              void* d_out, int out_size, void* d_ws, size_t ws_size,
                              hipStream_t stream) {
  const float* feat = (const float*)d_in[0];
  const int* labels = (const int*)d_in[1];
  float* out = (float*)d_out;

  char* ws = (char*)d_ws;
  unsigned short* protoB = (unsigned short*)ws;                  // 208*512*2 = 212992 B
  float* p2 = (float*)(ws + 212992);                             // 832 B
  float* partials = (float*)(ws + 214016);                       // 1024 floats = 4096 B
  float* psum = (float*)(ws + 222464);                           // 2*200*512*4 = 819200 B
  int* pcnt = (int*)(ws + 222464 + 819200);                      // 400 ints

  k_psum<<<2 * NCLS, 512, 0, stream>>>(feat, labels, psum, pcnt);
  k_pcomb<<<NPAD, 256, 0, stream>>>(psum, pcnt, protoB, p2);
  k_score<<<256, 256, 0, stream>>>(feat, labels, protoB, p2, partials);
  k_finish<<<1, 256, 0, stream>>>(partials, out);
}

// Round 5
// 50.215 us; speedup vs baseline: 1.8841x; 1.0891x over previous
//
#include <hip/hip_runtime.h>
#include <hip/hip_bf16.h>

#define NCLS 200
#define NPAD 208
#define NT 13          // 208 / 16 class tiles
#define DIM 512
#define NSAMP 32768
#define CAP 48         // per-wave list capacity (1024-sample segment, expect ~5)
#define BM 64          // sample rows per block
#define BK 32          // k-chunk per iteration
#define KIT 16         // DIM / BK
#define BSTR 40        // B LDS row stride in ushorts (80 B, 16B-aligned)

typedef __attribute__((ext_vector_type(4))) float f32x4;
typedef __attribute__((ext_vector_type(4))) int   i32x4;
typedef __attribute__((ext_vector_type(8))) short bf16x8;

__device__ inline short bf16s(float x) {
  __hip_bfloat16 h = __float2bfloat16(x);
  return *reinterpret_cast<short*>(&h);
}

__device__ inline bf16x8 pack8(f32x4 a, f32x4 b) {
  bf16x8 r;
  r[0] = bf16s(a[0]); r[1] = bf16s(a[1]); r[2] = bf16s(a[2]); r[3] = bf16s(a[3]);
  r[4] = bf16s(b[0]); r[5] = bf16s(b[1]); r[6] = bf16s(b[2]); r[7] = bf16s(b[3]);
  return r;
}

__device__ inline float sumsq(f32x4 a) {
  return a[0]*a[0] + a[1]*a[1] + a[2]*a[2] + a[3]*a[3];
}

// ---------------- Kernel 1a: per-(class, quarter) partial sums -----------------
// 800 blocks = 200 classes x 4 quarters, 512 threads = 8 waves.
// Wave w scans its 1024-sample segment barrier-free (intra-wave ballot rank),
// gathers+sums matching rows, one barrier to combine 8 wave partials.
__global__ __launch_bounds__(512) void k_psum(
    const float* __restrict__ feat, const int* __restrict__ labels,
    float* __restrict__ psum, int* __restrict__ pcnt)
{
  const int bx = blockIdx.x;
  const int c = bx >> 2, q = bx & 3;
  const int tid = threadIdx.x;
  const int lane = tid & 63;
  const int w = tid >> 6;

  __shared__ int   lists[8][CAP];
  __shared__ int   cnts[8];
  __shared__ float partial[8][DIM];

  int cnt = 0;
  const int segbase = q * (NSAMP / 4) + w * (NSAMP / 32);
  for (int i = 0; i < (NSAMP / 32) / 256; ++i) {          // 4 iters
    const int base = segbase + i * 256 + lane * 4;
    const i32x4 lab4 = *(const i32x4*)(labels + base);
    #pragma unroll
    for (int u = 0; u < 4; ++u) {
      const bool m = (lab4[u] == c);
      const unsigned long long bal = __ballot(m);
      if (m) {
        const int pos = cnt + __popcll(bal & ((1ull << lane) - 1ull));
        if (pos < CAP) lists[w][pos] = base + u;
      }
      cnt += __popcll(bal);
    }
  }
  if (cnt > CAP) cnt = CAP;
  if (lane == 0) cnts[w] = cnt;

  float acc[8];
  #pragma unroll
  for (int qq = 0; qq < 8; ++qq) acc[qq] = 0.f;
  for (int j = 0; j < cnt; ++j) {
    const int r = lists[w][j];
    const f32x4 a = *(const f32x4*)(feat + (size_t)r * DIM + lane * 8);
    const f32x4 b = *(const f32x4*)(feat + (size_t)r * DIM + lane * 8 + 4);
    acc[0] += a[0]; acc[1] += a[1]; acc[2] += a[2]; acc[3] += a[3];
    acc[4] += b[0]; acc[5] += b[1]; acc[6] += b[2]; acc[7] += b[3];
  }
  #pragma unroll
  for (int qq = 0; qq < 8; ++qq) partial[w][lane * 8 + qq] = acc[qq];
  __syncthreads();

  int total = 0;
  #pragma unroll
  for (int u = 0; u < 8; ++u) total += cnts[u];
  float s = 0.f;
  #pragma unroll
  for (int u = 0; u < 8; ++u) s += partial[u][tid];
  psum[(size_t)(q * NCLS + c) * DIM + tid] = s;
  if (tid == 0) pcnt[q * NCLS + c] = total;
}

// ---------------- Kernel 1b: combine quarters -> bf16 prototypes + p2 ----------
__global__ __launch_bounds__(256) void k_pcomb(
    const float* __restrict__ psum, const int* __restrict__ pcnt,
    unsigned short* __restrict__ protoB, float* __restrict__ p2out)
{
  const int c = blockIdx.x;
  const int tid = threadIdx.x;
  if (c >= NCLS) {
    protoB[c * DIM + tid] = 0;        // bf16 +0.0
    protoB[c * DIM + 256 + tid] = 0;
    if (tid == 0) p2out[c] = 1e30f;   // never wins argmin
    return;
  }
  __shared__ float red[256];
  float a0 = 0.f, a1 = 0.f;
  int total = 0;
  #pragma unroll
  for (int q = 0; q < 4; ++q) {        // fixed combine order: deterministic
    a0 += psum[(size_t)(q * NCLS + c) * DIM + tid];
    a1 += psum[(size_t)(q * NCLS + c) * DIM + 256 + tid];
    total += pcnt[q * NCLS + c];
  }
  const float inv = 1.0f / ((float)total + 1e-8f);   // counts + EPS
  const float p0 = a0 * inv, p1 = a1 * inv;
  protoB[c * DIM + tid] = (unsigned short)bf16s(p0);
  protoB[c * DIM + 256 + tid] = (unsigned short)bf16s(p1);

  red[tid] = p0 * p0 + p1 * p1;
  __syncthreads();
  for (int s = 128; s > 0; s >>= 1) {
    if (tid < s) red[tid] += red[tid + s];
    __syncthreads();
  }
  if (tid == 0) p2out[c] = red[0];
}

// ---------------- Kernel 2: LDS double-buffered MFMA GEMM + argmin + loss ------
// 512 blocks x 256 thr (4 waves) = 2 blocks/CU. Block: 64 samples x 208 classes.
// Per iter: issue next A/B global loads EARLY, compute MFMAs from buf[cur],
// write next chunk into buf^1 LATE, one barrier/iter. f2 exact fp32 by stagers.
__global__ __launch_bounds__(256) void k_score(
    const float* __restrict__ feat, const int* __restrict__ labels,
    const unsigned short* __restrict__ protoB, const float* __restrict__ p2,
    float* __restrict__ partials)
{
  __shared__ __align__(16) unsigned short As[2][BM * BK];     // bf16, swizzled units
  __shared__ __align__(16) unsigned short Bs[2][NPAD * BSTR]; // bf16, 80B row stride
  __shared__ float f2s[BM][4];

  const int tid = threadIdx.x;
  const int lane = tid & 63;
  const int w = tid >> 6;           // wave 0..3; wave owns rows [w*16, w*16+16)
  const int lr = lane & 15;
  const int kg = lane >> 4;

  const int blockRow = blockIdx.x * BM;

  // staging roles: A = 4 threads/row (row = tid>>2, part = tid&3, 8 floats each)
  const int arow = tid >> 2;
  const int apart = tid & 3;
  const float* agp = feat + (size_t)(blockRow + arow) * DIM + apart * 8;
  const int aunit = ((apart ^ (arow & 3)) * 8);   // XOR-swizzled 16B unit
  const int brow = tid;             // B: thread t stages proto row t (t < 208)
  const f32x4* bgp = (const f32x4*)(protoB + (size_t)brow * DIM);

  float f2part = 0.f;

  // ---- prologue: stage k-chunk 0 into buf 0 ----
  {
    const f32x4 a0 = *(const f32x4*)(agp);
    const f32x4 a1 = *(const f32x4*)(agp + 4);
    f2part += sumsq(a0) + sumsq(a1);
    *(bf16x8*)&As[0][arow * BK + aunit] = pack8(a0, a1);
    if (brow < NPAD) {
      const f32x4 b0 = bgp[0], b1 = bgp[1], b2 = bgp[2], b3 = bgp[3];
      *(f32x4*)&Bs[0][brow * BSTR + 0]  = b0;
      *(f32x4*)&Bs[0][brow * BSTR + 8]  = b1;
      *(f32x4*)&Bs[0][brow * BSTR + 16] = b2;
      *(f32x4*)&Bs[0][brow * BSTR + 24] = b3;
    }
  }
  __syncthreads();

  f32x4 acc[NT];
  #pragma unroll
  for (int n = 0; n < NT; ++n) acc[n] = f32x4{0.f, 0.f, 0.f, 0.f};

  const int r0 = w * 16 + lr;       // A-tile local row for this lane's frag
  const int ar0 = r0 * BK + ((kg ^ (r0 & 3)) * 8);

  #pragma unroll 2
  for (int t = 0; t < KIT; ++t) {
    const int cur = t & 1;
    f32x4 a0, a1, b0, b1, b2, b3;
    if (t < KIT - 1) {              // issue next-chunk global loads EARLY
      const float* ag = agp + (t + 1) * BK;
      a0 = *(const f32x4*)(ag);
      a1 = *(const f32x4*)(ag + 4);
      if (brow < NPAD) {
        const f32x4* bg = bgp + (t + 1) * 4;
        b0 = bg[0]; b1 = bg[1]; b2 = bg[2]; b3 = bg[3];
      }
    }
    // compute from buf[cur]
    const bf16x8 Af = *(const bf16x8*)&As[cur][ar0];
    #pragma unroll
    for (int n = 0; n < NT; ++n) {
      const bf16x8 Bf = *(const bf16x8*)&Bs[cur][(n * 16 + lr) * BSTR + kg * 8];
      acc[n] = __builtin_amdgcn_mfma_f32_16x16x32_bf16(Af, Bf, acc[n], 0, 0, 0);
    }
    if (t < KIT - 1) {              // write next chunk LATE (loads have landed)
      const int nb = cur ^ 1;
      f2part += sumsq(a0) + sumsq(a1);
      *(bf16x8*)&As[nb][arow * BK + aunit] = pack8(a0, a1);
      if (brow < NPAD) {
        *(f32x4*)&Bs[nb][brow * BSTR + 0]  = b0;
        *(f32x4*)&Bs[nb][brow * BSTR + 8]  = b1;
        *(f32x4*)&Bs[nb][brow * BSTR + 16] = b2;
        *(f32x4*)&Bs[nb][brow * BSTR + 24] = b3;
      }
      __syncthreads();
    }
  }

  // publish exact per-row-part f2; combine deterministically (fixed order)
  f2s[arow][apart] = f2part;
  __syncthreads();

  float p2v[NT];
  #pragma unroll
  for (int n = 0; n < NT; ++n) p2v[n] = p2[n * 16 + lr];

  float lsum = 0.f;
  #pragma unroll
  for (int r = 0; r < 4; ++r) {
    const int srow = kg * 4 + r;                    // C/D row within 16-tile
    const int lrow = w * 16 + srow;                 // block-local sample row
    const float f2v = (f2s[lrow][0] + f2s[lrow][1]) + (f2s[lrow][2] + f2s[lrow][3]);
    const int samp = blockRow + lrow;
    const int lab = labels[samp];
    float bestd = 1e38f; int bestc = 1 << 30;
    float posd = -1.f;
    #pragma unroll
    for (int n = 0; n < NT; ++n) {
      const int cidx = n * 16 + lr;                 // C/D col = class
      const float sc = acc[n][r];
      const float d2 = fmaxf(f2v + p2v[n] - 2.0f * sc, 0.0f);
      if (cidx == lab) posd = d2;
      else if (cidx < NCLS &&
               (d2 < bestd || (d2 == bestd && cidx < bestc))) { bestd = d2; bestc = cidx; }
    }
    #pragma unroll
    for (int sft = 1; sft < 16; sft <<= 1) {        // reduce within 16-lane group
      const float od = __shfl_xor(bestd, sft);
      const int   oc = __shfl_xor(bestc, sft);
      const float op = __shfl_xor(posd, sft);
      if (od < bestd || (od == bestd && oc < bestc)) { bestd = od; bestc = oc; }
      posd = fmaxf(posd, op);
    }
    const float dap = posd, dan = bestd;
    const float dapn = dap / (dap + dan + 1e-8f);
    const float dann = dan / (dapn + dan + 1e-8f);  // sequential normalization
    const float ps = fmaxf(0.f, 1.5f * dapn - 0.8f * dann + 0.6f);
    if (lr == 0) lsum += ps;
  }
  lsum += __shfl_xor(lsum, 16);
  lsum += __shfl_xor(lsum, 32);
  if (lane == 0) partials[blockIdx.x * 4 + w] = lsum;
}

// ---------------- Kernel 3: deterministic final reduce (2048 partials) ---------
__global__ __launch_bounds__(256) void k_finish(const float* __restrict__ partials,
                                                float* __restrict__ out)
{
  __shared__ float red[256];
  const int tid = threadIdx.x;
  float s = 0.f;
  #pragma unroll
  for (int j = 0; j < 8; ++j) s += partials[tid + j * 256];
  red[tid] = s;
  __syncthreads();
  for (int st = 128; st > 0; st >>= 1) {
    if (tid < st) red[tid] += red[tid + st];
    __syncthreads();
  }
  if (tid == 0) out[0] = fabsf(0.2f * (red[0] / (float)NSAMP));
}

extern "C" void kernel_launch(void* const* d_in, const int* in_sizes, int n_in,
                              void* d_out, int out_size, void* d_ws, size_t ws_size,
                              hipStream_t stream) {
  const float* feat = (const float*)d_in[0];
  const int* labels = (const int*)d_in[1];
  float* out = (float*)d_out;

  char* ws = (char*)d_ws;
  unsigned short* protoB = (unsigned short*)ws;                  // 208*512*2 = 212992 B
  float* p2 = (float*)(ws + 212992);                             // 832 B
  float* partials = (float*)(ws + 214016);                       // 2048 floats = 8192 B
  float* psum = (float*)(ws + 229376);                           // 4*200*512*4 = 1638400 B
  int* pcnt = (int*)(ws + 229376 + 1638400);                     // 800 ints

  k_psum<<<4 * NCLS, 512, 0, stream>>>(feat, labels, psum, pcnt);
  k_pcomb<<<NPAD, 256, 0, stream>>>(psum, pcnt, protoB, p2);
  k_score<<<512, 256, 0, stream>>>(feat, labels, protoB, p2, partials);
  k_finish<<<1, 256, 0, stream>>>(partials, out);
}

// Round 6
// 46.631 us; speedup vs baseline: 2.0289x; 1.0769x over previous
//
#include <hip/hip_runtime.h>
#include <hip/hip_bf16.h>

#define NCLS 200
#define NPADP 224       // padded proto rows = 14 x 16 (2 waves x 7 tiles)
#define NTW 7           // class tiles per wave
#define DIM 512
#define NSAMP 32768
#define NSEG 8          // psum sample segments
#define CAP 32          // per-wave list capacity (512-sample segment, expect ~2.6)
#define BM 64           // sample rows per block
#define BK 32           // k-chunk per iteration
#define KIT 16          // DIM / BK
#define BSTR 40         // B LDS row stride in ushorts (80 B)

typedef __attribute__((ext_vector_type(4))) float f32x4;
typedef __attribute__((ext_vector_type(4))) int   i32x4;
typedef __attribute__((ext_vector_type(8))) short bf16x8;

__device__ inline short bf16s(float x) {
  __hip_bfloat16 h = __float2bfloat16(x);
  return *reinterpret_cast<short*>(&h);
}

__device__ inline bf16x8 pack8(f32x4 a, f32x4 b) {
  bf16x8 r;
  r[0] = bf16s(a[0]); r[1] = bf16s(a[1]); r[2] = bf16s(a[2]); r[3] = bf16s(a[3]);
  r[4] = bf16s(b[0]); r[5] = bf16s(b[1]); r[6] = bf16s(b[2]); r[7] = bf16s(b[3]);
  return r;
}

__device__ inline float sumsq(f32x4 a) {
  return a[0]*a[0] + a[1]*a[1] + a[2]*a[2] + a[3]*a[3];
}

// Raw barrier: drain only LDS ops (cross-wave visibility); global loads stay
// in flight across the barrier (counted vmcnt at their use, not vmcnt(0)).
__device__ inline void bar_lgkm() {
  asm volatile("s_waitcnt lgkmcnt(0)" ::: "memory");
  __builtin_amdgcn_s_barrier();
}

// ---------------- Kernel 1a: per-(class, segment) partial sums -----------------
// 1600 blocks = 200 classes x 8 segments, 512 threads = 8 waves.
// Wave w scans its 512-sample sub-segment barrier-free (intra-wave ballot rank),
// gathers+sums matching rows (unroll-2, dual accumulators, fixed combine order).
__global__ __launch_bounds__(512) void k_psum(
    const float* __restrict__ feat, const int* __restrict__ labels,
    float* __restrict__ psum, int* __restrict__ pcnt)
{
  const int bx = blockIdx.x;
  const int c = bx >> 3, s = bx & 7;
  const int tid = threadIdx.x;
  const int lane = tid & 63;
  const int w = tid >> 6;

  __shared__ int   lists[8][CAP];
  __shared__ int   cnts[8];
  __shared__ float partial[8][DIM];

  int cnt = 0;
  const int segbase = s * (NSAMP / NSEG) + w * (NSAMP / NSEG / 8);
  #pragma unroll
  for (int i = 0; i < 2; ++i) {                           // 2 x 256 samples
    const int base = segbase + i * 256 + lane * 4;
    const i32x4 lab4 = *(const i32x4*)(labels + base);
    #pragma unroll
    for (int u = 0; u < 4; ++u) {
      const bool m = (lab4[u] == c);
      const unsigned long long bal = __ballot(m);
      if (m) {
        const int pos = cnt + __popcll(bal & ((1ull << lane) - 1ull));
        if (pos < CAP) lists[w][pos] = base + u;
      }
      cnt += __popcll(bal);
    }
  }
  if (cnt > CAP) cnt = CAP;
  if (lane == 0) cnts[w] = cnt;

  float aE[8], aO[8];
  #pragma unroll
  for (int q = 0; q < 8; ++q) { aE[q] = 0.f; aO[q] = 0.f; }
  int j = 0;
  for (; j + 2 <= cnt; j += 2) {
    const int r0 = lists[w][j], r1 = lists[w][j + 1];
    const f32x4 a0 = *(const f32x4*)(feat + (size_t)r0 * DIM + lane * 8);
    const f32x4 b0 = *(const f32x4*)(feat + (size_t)r0 * DIM + lane * 8 + 4);
    const f32x4 a1 = *(const f32x4*)(feat + (size_t)r1 * DIM + lane * 8);
    const f32x4 b1 = *(const f32x4*)(feat + (size_t)r1 * DIM + lane * 8 + 4);
    aE[0] += a0[0]; aE[1] += a0[1]; aE[2] += a0[2]; aE[3] += a0[3];
    aE[4] += b0[0]; aE[5] += b0[1]; aE[6] += b0[2]; aE[7] += b0[3];
    aO[0] += a1[0]; aO[1] += a1[1]; aO[2] += a1[2]; aO[3] += a1[3];
    aO[4] += b1[0]; aO[5] += b1[1]; aO[6] += b1[2]; aO[7] += b1[3];
  }
  if (j < cnt) {
    const int r0 = lists[w][j];
    const f32x4 a0 = *(const f32x4*)(feat + (size_t)r0 * DIM + lane * 8);
    const f32x4 b0 = *(const f32x4*)(feat + (size_t)r0 * DIM + lane * 8 + 4);
    aE[0] += a0[0]; aE[1] += a0[1]; aE[2] += a0[2]; aE[3] += a0[3];
    aE[4] += b0[0]; aE[5] += b0[1]; aE[6] += b0[2]; aE[7] += b0[3];
  }
  #pragma unroll
  for (int q = 0; q < 8; ++q) partial[w][lane * 8 + q] = aE[q] + aO[q];
  __syncthreads();

  int total = 0;
  #pragma unroll
  for (int u = 0; u < 8; ++u) total += cnts[u];
  float sv = 0.f;
  #pragma unroll
  for (int u = 0; u < 8; ++u) sv += partial[u][tid];
  psum[(size_t)(s * NCLS + c) * DIM + tid] = sv;
  if (tid == 0) pcnt[s * NCLS + c] = total;
}

// ---------------- Kernel 1b: combine segments -> chunk-major bf16 protos + p2 --
// protoI layout: [chunk 0..15][row 0..223][32 ushorts] (coalesced B staging).
__global__ __launch_bounds__(256) void k_pcomb(
    const float* __restrict__ psum, const int* __restrict__ pcnt,
    unsigned short* __restrict__ protoI, float* __restrict__ p2out)
{
  const int c = blockIdx.x;
  const int tid = threadIdx.x;
  const int d0 = tid, d1 = tid + 256;
  if (c >= NCLS) {
    protoI[((size_t)(d0 >> 5) * NPADP + c) * 32 + (d0 & 31)] = 0;  // bf16 +0.0
    protoI[((size_t)(d1 >> 5) * NPADP + c) * 32 + (d1 & 31)] = 0;
    if (tid == 0) p2out[c] = 1e30f;   // never wins argmin
    return;
  }
  __shared__ float red[256];
  float a0 = 0.f, a1 = 0.f;
  int total = 0;
  #pragma unroll
  for (int s = 0; s < NSEG; ++s) {     // fixed combine order: deterministic
    a0 += psum[(size_t)(s * NCLS + c) * DIM + d0];
    a1 += psum[(size_t)(s * NCLS + c) * DIM + d1];
    total += pcnt[s * NCLS + c];
  }
  const float inv = 1.0f / ((float)total + 1e-8f);   // counts + EPS
  const float p0 = a0 * inv, p1 = a1 * inv;
  protoI[((size_t)(d0 >> 5) * NPADP + c) * 32 + (d0 & 31)] = (unsigned short)bf16s(p0);
  protoI[((size_t)(d1 >> 5) * NPADP + c) * 32 + (d1 & 31)] = (unsigned short)bf16s(p1);

  red[tid] = p0 * p0 + p1 * p1;
  __syncthreads();
  for (int st = 128; st > 0; st >>= 1) {
    if (tid < st) red[tid] += red[tid + st];
    __syncthreads();
  }
  if (tid == 0) p2out[c] = red[0];
}

// ---------------- Kernel 2: depth-2 pipelined LDS MFMA GEMM + argmin + loss ----
// 512 blocks x 256 thr (4 waves, 2M x 2N) = 2 blocks/CU. Block: 64 rows x 224.
// Wave (wm,wn): rows [wm*32,+32), class tiles [wn*7,+7). Raw barriers drain
// lgkm only; global loads for chunk t+2 issued at iter t (named reg sets).
__global__ __launch_bounds__(256, 2) void k_score(
    const float* __restrict__ feat, const int* __restrict__ labels,
    const unsigned short* __restrict__ protoI, const float* __restrict__ p2,
    float* __restrict__ partials)
{
  __shared__ __align__(16) unsigned short As[2][BM * BK];     // bf16, swizzled
  __shared__ __align__(16) unsigned short Bs[2][NPADP * BSTR];// bf16, 80B stride
  __shared__ float f2s[BM][4];
  __shared__ float rd_d[2][BM];
  __shared__ int   rd_c[2][BM];
  __shared__ float rd_p[2][BM];

  const int tid = threadIdx.x;
  const int lane = tid & 63;
  const int w = tid >> 6;
  const int wm = w >> 1, wn = w & 1;
  const int lr = lane & 15;
  const int kg = lane >> 4;
  const int blockRow = blockIdx.x * BM;

  // A staging: 4 threads/row, 8 floats each; XOR-swizzled 16B units
  const int arow = tid >> 2, apart = tid & 3;
  const float* agp = feat + (size_t)(blockRow + arow) * DIM + apart * 8;
  const int aoff = arow * BK + ((apart ^ (arow & 3)) * 8);
  const int brow = tid;               // B: thread t stages proto row t (t<224)

#define ISSUE(T, A0, A1, B0, B1, B2, B3) do {                                   \
    const float* ag_ = agp + (T) * BK;                                          \
    A0 = *(const f32x4*)(ag_);                                                  \
    A1 = *(const f32x4*)(ag_ + 4);                                              \
    if (brow < NPADP) {                                                         \
      const f32x4* bg_ = (const f32x4*)(protoI + ((size_t)(T) * NPADP + brow) * 32); \
      B0 = bg_[0]; B1 = bg_[1]; B2 = bg_[2]; B3 = bg_[3];                       \
    }                                                                           \
  } while (0)

#define STORE(NB, A0, A1, B0, B1, B2, B3) do {                                  \
    f2part += sumsq(A0) + sumsq(A1);                                            \
    *(bf16x8*)&As[NB][aoff] = pack8(A0, A1);                                    \
    if (brow < NPADP) {                                                         \
      *(f32x4*)&Bs[NB][brow * BSTR + 0]  = B0;                                  \
      *(f32x4*)&Bs[NB][brow * BSTR + 8]  = B1;                                  \
      *(f32x4*)&Bs[NB][brow * BSTR + 16] = B2;                                  \
      *(f32x4*)&Bs[NB][brow * BSTR + 24] = B3;                                  \
    }                                                                           \
  } while (0)

#define COMPUTE(CUR) do {                                                       \
    const bf16x8 Af0 = *(const bf16x8*)&As[CUR][ar0];                           \
    const bf16x8 Af1 = *(const bf16x8*)&As[CUR][ar1];                           \
    _Pragma("unroll")                                                           \
    for (int n = 0; n < NTW; ++n) {                                             \
      const bf16x8 Bf = *(const bf16x8*)&Bs[CUR][boff + n * (16 * BSTR)];       \
      acc0[n] = __builtin_amdgcn_mfma_f32_16x16x32_bf16(Af0, Bf, acc0[n], 0, 0, 0); \
      acc1[n] = __builtin_amdgcn_mfma_f32_16x16x32_bf16(Af1, Bf, acc1[n], 0, 0, 0); \
    }                                                                           \
  } while (0)

  float f2part = 0.f;
  f32x4 aA0, aA1, bA0, bA1, bA2, bA3;   // set A (even chunks)
  f32x4 aB0, aB1, bB0, bB1, bB2, bB3;   // set B (odd chunks)

  // prologue: chunk0 -> buf0; issue chunk1
  ISSUE(0, aA0, aA1, bA0, bA1, bA2, bA3);
  STORE(0, aA0, aA1, bA0, bA1, bA2, bA3);
  ISSUE(1, aB0, aB1, bB0, bB1, bB2, bB3);
  bar_lgkm();

  f32x4 acc0[NTW], acc1[NTW];
  #pragma unroll
  for (int n = 0; n < NTW; ++n) {
    acc0[n] = f32x4{0.f, 0.f, 0.f, 0.f};
    acc1[n] = f32x4{0.f, 0.f, 0.f, 0.f};
  }

  const int r0v = wm * 32 + lr;
  const int r1v = r0v + 16;
  const int ar0 = r0v * BK + ((kg ^ (r0v & 3)) * 8);
  const int ar1 = r1v * BK + ((kg ^ (r1v & 3)) * 8);
  const int boff = (wn * (NTW * 16) + lr) * BSTR + kg * 8;

  #pragma unroll
  for (int p = 0; p < KIT / 2; ++p) {
    const int t0 = 2 * p, t1 = 2 * p + 1;
    // iter t0: compute buf0; issue chunk t0+2 -> setA; write chunk t0+1 (setB)
    COMPUTE(0);
    if (t0 + 2 < KIT) ISSUE(t0 + 2, aA0, aA1, bA0, bA1, bA2, bA3);
    STORE(1, aB0, aB1, bB0, bB1, bB2, bB3);
    bar_lgkm();
    // iter t1: compute buf1; issue chunk t1+2 -> setB; write chunk t1+1 (setA)
    COMPUTE(1);
    if (t1 + 2 < KIT) {
      ISSUE(t1 + 2, aB0, aB1, bB0, bB1, bB2, bB3);
      STORE(0, aA0, aA1, bA0, bA1, bA2, bA3);
      bar_lgkm();
    }
  }

  // exact per-row-part f2 (fixed combine order)
  f2s[arow][apart] = f2part;
  __syncthreads();

  float p2v[NTW];
  #pragma unroll
  for (int n = 0; n < NTW; ++n) p2v[n] = p2[wn * (NTW * 16) + n * 16 + lr];

  #pragma unroll
  for (int m = 0; m < 2; ++m) {
    #pragma unroll
    for (int r = 0; r < 4; ++r) {
      const int srow = kg * 4 + r;                    // C/D row within 16-tile
      const int lrow = wm * 32 + m * 16 + srow;       // block-local sample row
      const float f2v = (f2s[lrow][0] + f2s[lrow][1]) + (f2s[lrow][2] + f2s[lrow][3]);
      const int lab = labels[blockRow + lrow];
      float bestd = 1e38f; int bestc = 1 << 30;
      float posd = -1.f;
      #pragma unroll
      for (int n = 0; n < NTW; ++n) {
        const int cidx = wn * (NTW * 16) + n * 16 + lr;  // C/D col = class
        const float sc = (m == 0) ? acc0[n][r] : acc1[n][r];
        const float d2 = fmaxf(f2v + p2v[n] - 2.0f * sc, 0.0f);
        if (cidx == lab) posd = d2;
        else if (cidx < NCLS &&
                 (d2 < bestd || (d2 == bestd && cidx < bestc))) { bestd = d2; bestc = cidx; }
      }
      #pragma unroll
      for (int sft = 1; sft < 16; sft <<= 1) {        // 16-lane group reduce
        const float od = __shfl_xor(bestd, sft);
        const int   oc = __shfl_xor(bestc, sft);
        const float op = __shfl_xor(posd, sft);
        if (od < bestd || (od == bestd && oc < bestc)) { bestd = od; bestc = oc; }
        posd = fmaxf(posd, op);
      }
      if (lr == 0) {                                  // publish per-half result
        rd_d[wn][lrow] = bestd; rd_c[wn][lrow] = bestc; rd_p[wn][lrow] = posd;
      }
    }
  }
  __syncthreads();

  if (tid < BM) {                                     // wave 0: combine + loss
    const float d0 = rd_d[0][tid], d1 = rd_d[1][tid];
    const int   c0 = rd_c[0][tid], c1 = rd_c[1][tid];
    float bestd; int bestc;
    if (d1 < d0 || (d1 == d0 && c1 < c0)) { bestd = d1; bestc = c1; }
    else                                  { bestd = d0; bestc = c0; }
    (void)bestc;
    const float posd = fmaxf(rd_p[0][tid], rd_p[1][tid]);
    const float dap = posd, dan = bestd;
    const float dapn = dap / (dap + dan + 1e-8f);
    const float dann = dan / (dapn + dan + 1e-8f);    // sequential normalization
    float v = fmaxf(0.f, 1.5f * dapn - 0.8f * dann + 0.6f);
    #pragma unroll
    for (int sft = 1; sft < 64; sft <<= 1) v += __shfl_xor(v, sft);
    if (tid == 0) partials[blockIdx.x] = v;
  }
#undef ISSUE
#undef STORE
#undef COMPUTE
}

// ---------------- Kernel 3: deterministic final reduce (512 partials) ----------
__global__ __launch_bounds__(256) void k_finish(const float* __restrict__ partials,
                                                float* __restrict__ out)
{
  __shared__ float red[256];
  const int tid = threadIdx.x;
  red[tid] = partials[tid] + partials[tid + 256];
  __syncthreads();
  for (int st = 128; st > 0; st >>= 1) {
    if (tid < st) red[tid] += red[tid + st];
    __syncthreads();
  }
  if (tid == 0) out[0] = fabsf(0.2f * (red[0] / (float)NSAMP));
}

extern "C" void kernel_launch(void* const* d_in, const int* in_sizes, int n_in,
                              void* d_out, int out_size, void* d_ws, size_t ws_size,
                              hipStream_t stream) {
  const float* feat = (const float*)d_in[0];
  const int* labels = (const int*)d_in[1];
  float* out = (float*)d_out;

  char* ws = (char*)d_ws;
  unsigned short* protoI = (unsigned short*)ws;          // 16*224*32*2 = 229376 B
  float* p2 = (float*)(ws + 229376);                     // 224 floats
  float* partials = (float*)(ws + 230400);               // 512 floats
  float* psum = (float*)(ws + 232448);                   // 8*200*512*4 = 3276800 B
  int* pcnt = (int*)(ws + 3509248);                      // 1600 ints

  k_psum<<<NSEG * NCLS, 512, 0, stream>>>(feat, labels, psum, pcnt);
  k_pcomb<<<NPADP, 256, 0, stream>>>(psum, pcnt, protoI, p2);
  k_score<<<512, 256, 0, stream>>>(feat, labels, protoI, p2, partials);
  k_finish<<<1, 256, 0, stream>>>(partials, out);
}